// Round 6
// baseline (5081.988 us; speedup 1.0000x reference)
//
#include <hip/hip_runtime.h>

#define N_NODES 2048
#define KSEL 50

typedef float v2f __attribute__((ext_vector_type(2)));

// ---- order-preserving fp32 <-> uint map (monotone: bigger float => bigger uint)
__device__ __forceinline__ unsigned ford(float f) {
  unsigned b = __float_as_uint(f);
  return b ^ ((b & 0x80000000u) ? 0xFFFFFFFFu : 0x80000000u);
}
__device__ __forceinline__ float funord(unsigned u) {
  unsigned b = (u & 0x80000000u) ? (u ^ 0x80000000u) : ~u;
  return __uint_as_float(b);
}

// hist storage: bin b, sub-counter s (s = lane&1): word (b&63)*8 + (b>>6)*2 + s.
// Scan: lane reads words [lane*8, lane*8+8) = bins {g*64+lane} x {s} as 2x uint4.
#define HROW 516  // 512 + 4 pad: rows stagger 4 banks, 16B-aligned
__device__ __forceinline__ int hidx(unsigned b, int s) {
  return (int)(((b & 63u) << 3) | ((b >> 6) << 1)) | s;
}

// shared single-layer MLP tile: acc[16] = relu(bias + xs^T W), xs transposed layout
__device__ __forceinline__ void mlp_layer(float acc[16], const float* xs,
                                          const float* Ws, const float* bs,
                                          int r, int cg) {
  const float4* Ws4 = (const float4*)Ws;
#pragma unroll
  for (int i = 0; i < 16; ++i) acc[i] = bs[cg * 16 + i];
#pragma unroll 8
  for (int k = 0; k < 64; ++k) {
    float xv = xs[k * 65 + r];                   // banks (k+r)%32: 2-way, free
    float4 w0 = Ws4[k * 16 + cg * 4 + 0];        // wave-uniform broadcast
    float4 w1 = Ws4[k * 16 + cg * 4 + 1];
    float4 w2 = Ws4[k * 16 + cg * 4 + 2];
    float4 w3 = Ws4[k * 16 + cg * 4 + 3];
    acc[0]  += xv * w0.x; acc[1]  += xv * w0.y; acc[2]  += xv * w0.z; acc[3]  += xv * w0.w;
    acc[4]  += xv * w1.x; acc[5]  += xv * w1.y; acc[6]  += xv * w1.z; acc[7]  += xv * w1.w;
    acc[8]  += xv * w2.x; acc[9]  += xv * w2.y; acc[10] += xv * w2.z; acc[11] += xv * w2.w;
    acc[12] += xv * w3.x; acc[13] += xv * w3.y; acc[14] += xv * w3.z; acc[15] += xv * w3.w;
  }
#pragma unroll
  for (int i = 0; i < 16; ++i) acc[i] = fmaxf(acc[i], 0.f);
}

// Fused embedding: h1=relu(x@w0+b0); h2=relu(h1@w1+b1) -> A, AT; msg0=relu(h2@wm+bm) -> M
__global__ __launch_bounds__(256) void emb3_kernel(
    const float* __restrict__ x,
    const float* __restrict__ ew0, const float* __restrict__ eb0,
    const float* __restrict__ ew1, const float* __restrict__ eb1,
    const float* __restrict__ wmm, const float* __restrict__ bmm,
    float* __restrict__ outA, float* __restrict__ outAT, float* __restrict__ outM)
{
  const int tid = threadIdx.x;
  const int r = tid & 63, cg = tid >> 6;
  const size_t rowbase = (size_t)blockIdx.x * 64;
  __shared__ float xs[64 * 65];       // transposed: xs[c*65 + row]
  __shared__ float Ws[64 * 64];
  __shared__ float bs[64];
  float acc[16];

#pragma unroll
  for (int i = 0; i < 16; ++i) {
    int idx = tid + 256 * i;
    xs[(idx & 63) * 65 + (idx >> 6)] = x[rowbase * 64 + idx];
    Ws[idx] = ew0[idx];
  }
  if (tid < 64) bs[tid] = eb0[tid];
  __syncthreads();
  mlp_layer(acc, xs, Ws, bs, r, cg);             // h1
  __syncthreads();
#pragma unroll
  for (int i = 0; i < 16; ++i) {
    xs[(cg * 16 + i) * 65 + r] = acc[i];
    Ws[tid + 256 * i] = ew1[tid + 256 * i];
  }
  if (tid < 64) bs[tid] = eb1[tid];
  __syncthreads();
  mlp_layer(acc, xs, Ws, bs, r, cg);             // h2
  {
    float4* o4 = (float4*)(outA + (rowbase + r) * 64 + cg * 16);
#pragma unroll
    for (int q = 0; q < 4; ++q)
      o4[q] = make_float4(acc[q*4+0], acc[q*4+1], acc[q*4+2], acc[q*4+3]);
  }
  __syncthreads();
#pragma unroll
  for (int i = 0; i < 16; ++i) {
    xs[(cg * 16 + i) * 65 + r] = acc[i];
    Ws[tid + 256 * i] = wmm[tid + 256 * i];
  }
  if (tid < 64) bs[tid] = bmm[tid];
  __syncthreads();
  {   // flush AT (h2 transposed, feature-major)
    const size_t bb = rowbase >> 11;
    const int nbase = (int)(rowbase & 2047);
    const int c = tid >> 2, seg = tid & 3;
    float* oT = outAT + bb * 64 * N_NODES + (size_t)c * N_NODES + nbase + seg * 16;
#pragma unroll
    for (int q = 0; q < 4; ++q)
      ((float4*)oT)[q] = make_float4(xs[c*65+seg*16+q*4+0], xs[c*65+seg*16+q*4+1],
                                     xs[c*65+seg*16+q*4+2], xs[c*65+seg*16+q*4+3]);
  }
  mlp_layer(acc, xs, Ws, bs, r, cg);             // msg0
  {
    float4* o4 = (float4*)(outM + (rowbase + r) * 64 + cg * 16);
#pragma unroll
    for (int q = 0; q < 4; ++q)
      o4[q] = make_float4(acc[q*4+0], acc[q*4+1], acc[q*4+2], acc[q*4+3]);
  }
}

// plain single-layer linrelu (msg1)
__global__ __launch_bounds__(256) void linrelu_kernel(
    const float* __restrict__ in, const float* __restrict__ W,
    const float* __restrict__ bias, float* __restrict__ out)
{
  const int tid = threadIdx.x;
  const int r = tid & 63, cg = tid >> 6;
  const size_t rowbase = (size_t)blockIdx.x * 64;
  __shared__ float xs[64 * 65];
  __shared__ float Ws[64 * 64];
  __shared__ float bs[64];
  float acc[16];
#pragma unroll
  for (int i = 0; i < 16; ++i) {
    int idx = tid + 256 * i;
    xs[(idx & 63) * 65 + (idx >> 6)] = in[rowbase * 64 + idx];
    Ws[idx] = W[idx];
  }
  if (tid < 64) bs[tid] = bias[tid];
  __syncthreads();
  mlp_layer(acc, xs, Ws, bs, r, cg);
  float4* o4 = (float4*)(out + (rowbase + r) * 64 + cg * 16);
#pragma unroll
  for (int q = 0; q < 4; ++q)
    o4[q] = make_float4(acc[q*4+0], acc[q*4+1], acc[q*4+2], acc[q*4+3]);
}

// Fused: S = h_tile . h^T (8 rows x 2048). 512 threads/block, 32 values/thread
// (fits 128-reg budget at 2 blocks/CU: no spills). Packed-fp32 FMA, SGPR row
// operands, adaptive radix select (prefix skip + probe), ballot extract.
template <bool FINAL>
__global__ __launch_bounds__(512, 4) void mp_kernel(
    const float* __restrict__ h, const float* __restrict__ hT,
    const float* __restrict__ msg,
    const float* __restrict__ wu, const float* __restrict__ bu,
    float* __restrict__ outp, float* __restrict__ outT)
{
  const int tid = threadIdx.x;
  const int lane = tid & 63;
  const int w64 = tid >> 6;               // 8 waves
  const int bid = blockIdx.x;
  const int b = bid & 7;                  // round-robin blockIdx->XCD: 1 batch/XCD
  const int n0 = (bid >> 3) * 8;

  __shared__ float hrL[8 * 64];           // MP epilogue only
  __shared__ unsigned hist[8][HROW];      // sub-counter radix histograms
  __shared__ unsigned Lrow[8], pvS[8], TrowS[8], KcurS[8];
  __shared__ int shS[8], modeS[8];        // 0=HIST 1=PROBE 2=DONE
  __shared__ int sDone;
  __shared__ unsigned gtc[8], eqc[8];
  __shared__ unsigned LwMin[8][8], LwMax[8][8];   // [wave][row]
  __shared__ int seli[8][64];
  __shared__ float selv[8][64];
  __shared__ int eqlist[8][64];
  __shared__ float aggb[8 * 64];
  __shared__ float ot[64 * 9];

  const float* hb  = h  + (size_t)b * N_NODES * 64;
  const float* hTb = hT + (size_t)b * 64 * N_NODES;
  const float* colp = hTb + 4 * tid;      // 512 lanes x 4 cols = 2048

  float4 cur0, nxt0;
  cur0 = *(const float4*)(colp);

  if (!FINAL) hrL[tid] = hb[(size_t)n0 * 64 + tid];
  if (tid == 0) sDone = 0;
  if (tid < 8) { gtc[tid] = 0; eqc[tid] = 0; }
  for (int i = tid; i < 8 * HROW; i += 512) (&hist[0][0])[i] = 0;
  __syncthreads();

  // ---- S tile: value (r,e) in acc2[r*2+(e>>1)][e&1], column m = 4*tid + e
  v2f acc2[16];
#pragma unroll
  for (int i = 0; i < 16; ++i) { acc2[i][0] = 0.f; acc2[i][1] = 0.f; }

  const float* hrow = hb + (size_t)n0 * 64;   // block-uniform -> s_load path
  const float* cp = colp;

  for (int k4 = 0; k4 < 16; ++k4) {
    float4 a[8];
#pragma unroll
    for (int r = 0; r < 8; ++r)
      a[r] = *(const float4*)(hrow + r * 64 + k4 * 4);   // uniform scalar loads
#pragma unroll
    for (int kk = 0; kk < 4; ++kk) {
      const int k = k4 * 4 + kk;
      if (k < 63) nxt0 = *(const float4*)(cp + 2048);     // prefetch k+1
      v2f c00 = {cur0.x, cur0.y}, c01 = {cur0.z, cur0.w};
#pragma unroll
      for (int r = 0; r < 8; ++r) {
        const float ar = ((const float*)&a[r])[kk];
        v2f as = {ar, ar};
        acc2[r*2+0] = __builtin_elementwise_fma(as, c00, acc2[r*2+0]);
        acc2[r*2+1] = __builtin_elementwise_fma(as, c01, acc2[r*2+1]);
      }
      cur0 = nxt0;
      cp += 2048;
    }
  }

  // ---- convert to ordered uints; acc2 dies here (32 live values after)
  unsigned u[32];
#pragma unroll
  for (int r = 0; r < 8; ++r)
#pragma unroll
    for (int e = 0; e < 4; ++e)
      u[r * 4 + e] = ford(acc2[r*2 + (e>>1)][e & 1]);

  // ---- prefilter: per row, L = max over waves of (wave-min of lane-max-of-4)
  //      guarantees >=64 candidates >= L, so L <= T; M = row max.
#pragma unroll
  for (int rr = 0; rr < 8; ++rr) {
    unsigned mx = u[rr * 4];
#pragma unroll
    for (int j = 1; j < 4; ++j) { unsigned v = u[rr*4+j]; mx = mx > v ? mx : v; }
    unsigned mn = mx, mxx = mx;
#pragma unroll
    for (int off = 32; off >= 1; off >>= 1) {
      unsigned o1 = (unsigned)__shfl_xor((int)mn, off, 64);
      unsigned o2 = (unsigned)__shfl_xor((int)mxx, off, 64);
      mn = mn < o1 ? mn : o1;
      mxx = mxx > o2 ? mxx : o2;
    }
    if (lane == 0) { LwMin[w64][rr] = mn; LwMax[w64][rr] = mxx; }
  }
  __syncthreads();
  if (tid < 8) {
    unsigned L = LwMin[0][tid], M = LwMax[0][tid];
#pragma unroll
    for (int w = 1; w < 8; ++w) {
      unsigned l = LwMin[w][tid], m = LwMax[w][tid];
      L = L > l ? L : l; M = M > m ? M : m;
    }
    Lrow[tid] = L;
    unsigned d = L ^ M;
    if (d == 0) {                       // >=64 exact copies of M: T = M
      modeS[tid] = 2; TrowS[tid] = M; atomicAdd(&sDone, 1);
    } else {
      int skipb = __builtin_clz(d) >> 3;          // common prefix, bytes
      int sh = 24 - 8 * skipb;                    // in {0,8,16,24}
      shS[tid] = sh;
      pvS[tid] = (unsigned)(((unsigned long long)L) >> (sh + 8));
      modeS[tid] = 0; KcurS[tid] = KSEL;
    }
  }
  __syncthreads();

  // ---- adaptive radix select: data-dependent #levels, probe when bin count==1
  const int sub = lane & 1;
  for (int it = 0; it < 4; ++it) {
    if (sDone == 8) break;
    // -- populate / probe phase
#pragma unroll
    for (int r = 0; r < 8; ++r) {
      const int md = modeS[r];
      if (md == 2) continue;
      const unsigned Lv = Lrow[r];
      const unsigned pr = pvS[r];
      const int shr = shS[r];
      if (md == 0) {
        unsigned* hrw = hist[r];
#pragma unroll
        for (int j = 0; j < 4; ++j) {
          unsigned v = u[r * 4 + j];
          bool act = (v >= Lv) &&
                     ((unsigned)(((unsigned long long)v) >> (shr + 8)) == pr);
          if (act) atomicAdd(&hrw[hidx((v >> shr) & 255u, sub)], 1u);
        }
      } else {                                    // PROBE: unique candidate = T
#pragma unroll
        for (int j = 0; j < 4; ++j) {
          unsigned v = u[r * 4 + j];
          if (v >= Lv &&
              ((unsigned)(((unsigned long long)v) >> (shr + 8)) == pr)) {
            TrowS[r] = v; modeS[r] = 2; atomicAdd(&sDone, 1);
          }
        }
      }
    }
    __syncthreads();
    // -- scan phase: wave w64 handles row w64
    {
      const int rr = w64;
      if (modeS[rr] == 0) {
        unsigned* hrw = hist[rr];
        uint4 q0 = *(const uint4*)&hrw[lane * 8];
        uint4 q1 = *(const uint4*)&hrw[lane * 8 + 4];
        *(uint4*)&hrw[lane * 8]     = make_uint4(0,0,0,0);
        *(uint4*)&hrw[lane * 8 + 4] = make_uint4(0,0,0,0);
        unsigned c0 = q0.x + q0.y, c1 = q0.z + q0.w;
        unsigned c2 = q1.x + q1.y, c3 = q1.z + q1.w;
        unsigned s0 = c0, s1 = c1, s2 = c2, s3 = c3;      // suffix over lanes
#pragma unroll
        for (int off = 1; off < 64; off <<= 1) {
          unsigned t0=__shfl_down((int)s0,off,64), t1=__shfl_down((int)s1,off,64);
          unsigned t2=__shfl_down((int)s2,off,64), t3=__shfl_down((int)s3,off,64);
          if (lane + off < 64) { s0+=t0; s1+=t1; s2+=t2; s3+=t3; }
        }
        unsigned T1=(unsigned)__shfl((int)s1,0,64), T2=(unsigned)__shfl((int)s2,0,64);
        unsigned T3=(unsigned)__shfl((int)s3,0,64);
        const unsigned Kc = KcurS[rr];
        unsigned cA[4] = {c0, c1, c2, c3};
        unsigned AA[4] = {s0 - c0 + T1 + T2 + T3, s1 - c1 + T2 + T3,
                          s2 - c2 + T3,           s3 - c3};
#pragma unroll
        for (int g = 0; g < 4; ++g) {
          if (AA[g] < Kc && Kc <= AA[g] + cA[g]) {  // unique (lane,g) fires
            unsigned bin = (unsigned)(g * 64 + lane);
            unsigned pvn = (pvS[rr] << 8) | bin;
            int shn = shS[rr] - 8;
            KcurS[rr] = Kc - AA[g];
            if (shn < 0) { TrowS[rr] = pvn; modeS[rr] = 2; atomicAdd(&sDone, 1); }
            else         { pvS[rr] = pvn; shS[rr] = shn;
                           if (cA[g] == 1) modeS[rr] = 1; }
          }
        }
      }
    }
    __syncthreads();
  }

  // ---- extract winners (> T) and tie candidates (== T), ballot-compacted
#pragma unroll
  for (int r = 0; r < 8; ++r) {
    const unsigned T = TrowS[r];
#pragma unroll
    for (int j = 0; j < 4; ++j) {
      const unsigned v = u[r * 4 + j];
      const int m = 4 * tid + j;
      unsigned long long mk = __ballot(v > T);
      if (mk) {
        int fs = __ffsll(mk) - 1;
        unsigned base = 0;
        if (lane == fs) base = atomicAdd(&gtc[r], (unsigned)__popcll(mk));
        base = (unsigned)__shfl((int)base, fs, 64);
        if (v > T) {
          int pos = (int)base + __popcll(mk & ((1ULL << lane) - 1ULL));
          seli[r][pos] = m; selv[r][pos] = funord(v);
        }
      }
      unsigned long long mk2 = __ballot(v == T);
      if (mk2) {
        int fs = __ffsll(mk2) - 1;
        unsigned base = 0;
        if (lane == fs) base = atomicAdd(&eqc[r], (unsigned)__popcll(mk2));
        base = (unsigned)__shfl((int)base, fs, 64);
        if (v == T) {
          int pos = (int)base + __popcll(mk2 & ((1ULL << lane) - 1ULL));
          if (pos < 64) eqlist[r][pos] = m;
        }
      }
    }
  }
  __syncthreads();

  // ---- resolve ties: `need` smallest indices among equals (jax order)
  if (tid < 8) {
    const int r = tid;
    const int g = (int)gtc[r];
    const int need = KSEL - g;
    const int e = (eqc[r] < 64u) ? (int)eqc[r] : 64;
    const float Tf = funord(TrowS[r]);
    for (int t = 0; t < need; ++t) {
      int bestp = -1, bestm = 0x7FFFFFFF;
      for (int i = 0; i < e; ++i) {
        int mm = eqlist[r][i];
        if (mm < bestm) { bestm = mm; bestp = i; }
      }
      if (bestp < 0) break;
      eqlist[r][bestp] = 0x7FFFFFFF;
      seli[r][g + t] = bestm;
      selv[r][g + t] = Tf;
    }
  }
  __syncthreads();

  if constexpr (FINAL) {
    float* ob = outp + ((size_t)b * N_NODES + n0) * N_NODES;
#pragma unroll
    for (int r = 0; r < 8; ++r) {
      const unsigned T = TrowS[r];
      const int g = (int)gtc[r];
      const int need = KSEL - g;
      float4 w; float* wf = (float*)&w;
#pragma unroll
      for (int e = 0; e < 4; ++e) {
        const unsigned v = u[r * 4 + e];
        const int m = 4 * tid + e;
        bool keep = v > T;
        if (v == T) {
          for (int i = 0; i < need; ++i)
            if (seli[r][g + i] == m) { keep = true; break; }
        }
        wf[e] = keep ? funord(v) : 0.f;
      }
      *(float4*)(ob + (size_t)r * N_NODES + 4 * tid) = w;
    }
  } else {
    // sparse aggregation: one (row, feature) per thread
    {
      const int r = w64;
      const int f = lane;
      const float* msgb = msg + (size_t)b * N_NODES * 64;
      float a = 0.f;
      for (int i = 0; i < KSEL; ++i) {
        int mi = seli[r][i];                      // wave-uniform LDS broadcast
        float vv = selv[r][i];
        a += vv * msgb[(size_t)mi * 64 + f];      // coalesced 256B per wave
      }
      aggb[r * 64 + f] = a;
    }
    __syncthreads();
    // update MLP: one output (r, c) per thread
    const int r = w64;
    const int c = lane;
    float s = bu[c];
#pragma unroll 8
    for (int jj = 0; jj < 64; ++jj)
      s += hrL[r * 64 + jj] * wu[jj * 64 + c];    // LDS broadcast x coalesced
#pragma unroll 8
    for (int jj = 0; jj < 64; ++jj)
      s += aggb[r * 64 + jj] * wu[(64 + jj) * 64 + c];
    s = fmaxf(s, 0.f);
    outp[((size_t)b * N_NODES + n0 + r) * 64 + c] = s;
    ot[c * 9 + r] = s;                            // stride 9: conflict-free
    __syncthreads();
    {                                             // flush h2T (32B segments)
      int f = tid >> 3, rr = tid & 7;
      outT[(size_t)b * 64 * N_NODES + (size_t)f * N_NODES + n0 + rr] = ot[f * 9 + rr];
    }
  }
}

extern "C" void kernel_launch(void* const* d_in, const int* in_sizes, int n_in,
                              void* d_out, int out_size, void* d_ws, size_t ws_size,
                              hipStream_t stream)
{
  (void)in_sizes; (void)n_in; (void)out_size; (void)ws_size;
  const float* x   = (const float*)d_in[0];
  const float* ew0 = (const float*)d_in[1];
  const float* eb0 = (const float*)d_in[2];
  const float* ew1 = (const float*)d_in[3];
  const float* eb1 = (const float*)d_in[4];
  const float* w0m = (const float*)d_in[5];
  const float* b0m = (const float*)d_in[6];
  const float* w0u = (const float*)d_in[7];
  const float* b0u = (const float*)d_in[8];
  const float* w1m = (const float*)d_in[9];
  const float* b1m = (const float*)d_in[10];
  const float* w1u = (const float*)d_in[11];
  const float* b1u = (const float*)d_in[12];
  float* out = (float*)d_out;
  float* ws = (float*)d_ws;

  const size_t BUF = (size_t)8 * N_NODES * 64;  // 4 MB each, 20 MB total
  float* A   = ws;
  float* AT  = ws + 1 * BUF;
  float* Bf  = ws + 2 * BUF;
  float* BfT = ws + 3 * BUF;
  float* C   = ws + 4 * BUF;

  // fused embedding (2 layers) + msg0
  emb3_kernel<<<256, 256, 0, stream>>>(x, ew0, eb0, ew1, eb1, w0m, b0m, A, AT, C);

  // MP layer 0 (consumes msg0=C, produces Bf/BfT)
  mp_kernel<false><<<2048, 512, 0, stream>>>(A, AT, C, w0u, b0u, Bf, BfT);

  // msg1
  linrelu_kernel<<<256, 256, 0, stream>>>(Bf, w1m, b1m, C);

  // MP layer 1
  mp_kernel<false><<<2048, 512, 0, stream>>>(Bf, BfT, C, w1u, b1u, A, AT);

  // final dense top-k adjacency
  mp_kernel<true><<<2048, 512, 0, stream>>>(A, AT, nullptr, nullptr, nullptr, out, nullptr);
}

// Round 7
// 748.984 us; speedup vs baseline: 6.7852x; 6.7852x over previous
//
#include <hip/hip_runtime.h>

#define N_NODES 2048
#define KSEL 50

typedef float v2f __attribute__((ext_vector_type(2)));

// ---- order-preserving fp32 <-> uint map (monotone: bigger float => bigger uint)
__device__ __forceinline__ unsigned ford(float f) {
  unsigned b = __float_as_uint(f);
  return b ^ ((b & 0x80000000u) ? 0xFFFFFFFFu : 0x80000000u);
}
__device__ __forceinline__ float funord(unsigned u) {
  unsigned b = (u & 0x80000000u) ? (u ^ 0x80000000u) : ~u;
  return __uint_as_float(b);
}

// hist storage: bin b, sub-counter s (s = lane&1): word (b&63)*8 + (b>>6)*2 + s.
// Scan: lane reads words [lane*8, lane*8+8) = bins {g*64+lane} x {s} as 2x uint4.
#define HROW 516
__device__ __forceinline__ int hidx(unsigned b, int s) {
  return (int)(((b & 63u) << 3) | ((b >> 6) << 1)) | s;
}

// shared single-layer MLP tile: acc[16] = relu(bias + xs^T W), xs transposed layout
__device__ __forceinline__ void mlp_layer(float acc[16], const float* xs,
                                          const float* Ws, const float* bs,
                                          int r, int cg) {
  const float4* Ws4 = (const float4*)Ws;
#pragma unroll
  for (int i = 0; i < 16; ++i) acc[i] = bs[cg * 16 + i];
#pragma unroll 8
  for (int k = 0; k < 64; ++k) {
    float xv = xs[k * 65 + r];
    float4 w0 = Ws4[k * 16 + cg * 4 + 0];
    float4 w1 = Ws4[k * 16 + cg * 4 + 1];
    float4 w2 = Ws4[k * 16 + cg * 4 + 2];
    float4 w3 = Ws4[k * 16 + cg * 4 + 3];
    acc[0]  += xv * w0.x; acc[1]  += xv * w0.y; acc[2]  += xv * w0.z; acc[3]  += xv * w0.w;
    acc[4]  += xv * w1.x; acc[5]  += xv * w1.y; acc[6]  += xv * w1.z; acc[7]  += xv * w1.w;
    acc[8]  += xv * w2.x; acc[9]  += xv * w2.y; acc[10] += xv * w2.z; acc[11] += xv * w2.w;
    acc[12] += xv * w3.x; acc[13] += xv * w3.y; acc[14] += xv * w3.z; acc[15] += xv * w3.w;
  }
#pragma unroll
  for (int i = 0; i < 16; ++i) acc[i] = fmaxf(acc[i], 0.f);
}

// Fused embedding: h1=relu(x@w0+b0); h2=relu(h1@w1+b1) -> A, AT; msg0=relu(h2@wm+bm) -> M
__global__ __launch_bounds__(256) void emb3_kernel(
    const float* __restrict__ x,
    const float* __restrict__ ew0, const float* __restrict__ eb0,
    const float* __restrict__ ew1, const float* __restrict__ eb1,
    const float* __restrict__ wmm, const float* __restrict__ bmm,
    float* __restrict__ outA, float* __restrict__ outAT, float* __restrict__ outM)
{
  const int tid = threadIdx.x;
  const int r = tid & 63, cg = tid >> 6;
  const size_t rowbase = (size_t)blockIdx.x * 64;
  __shared__ float xs[64 * 65];
  __shared__ float Ws[64 * 64];
  __shared__ float bs[64];
  float acc[16];

#pragma unroll
  for (int i = 0; i < 16; ++i) {
    int idx = tid + 256 * i;
    xs[(idx & 63) * 65 + (idx >> 6)] = x[rowbase * 64 + idx];
    Ws[idx] = ew0[idx];
  }
  if (tid < 64) bs[tid] = eb0[tid];
  __syncthreads();
  mlp_layer(acc, xs, Ws, bs, r, cg);             // h1
  __syncthreads();
#pragma unroll
  for (int i = 0; i < 16; ++i) {
    xs[(cg * 16 + i) * 65 + r] = acc[i];
    Ws[tid + 256 * i] = ew1[tid + 256 * i];
  }
  if (tid < 64) bs[tid] = eb1[tid];
  __syncthreads();
  mlp_layer(acc, xs, Ws, bs, r, cg);             // h2
  {
    float4* o4 = (float4*)(outA + (rowbase + r) * 64 + cg * 16);
#pragma unroll
    for (int q = 0; q < 4; ++q)
      o4[q] = make_float4(acc[q*4+0], acc[q*4+1], acc[q*4+2], acc[q*4+3]);
  }
  __syncthreads();
#pragma unroll
  for (int i = 0; i < 16; ++i) {
    xs[(cg * 16 + i) * 65 + r] = acc[i];
    Ws[tid + 256 * i] = wmm[tid + 256 * i];
  }
  if (tid < 64) bs[tid] = bmm[tid];
  __syncthreads();
  {   // flush AT (h2 transposed, feature-major)
    const size_t bb = rowbase >> 11;
    const int nbase = (int)(rowbase & 2047);
    const int c = tid >> 2, seg = tid & 3;
    float* oT = outAT + bb * 64 * N_NODES + (size_t)c * N_NODES + nbase + seg * 16;
#pragma unroll
    for (int q = 0; q < 4; ++q)
      ((float4*)oT)[q] = make_float4(xs[c*65+seg*16+q*4+0], xs[c*65+seg*16+q*4+1],
                                     xs[c*65+seg*16+q*4+2], xs[c*65+seg*16+q*4+3]);
  }
  mlp_layer(acc, xs, Ws, bs, r, cg);             // msg0
  {
    float4* o4 = (float4*)(outM + (rowbase + r) * 64 + cg * 16);
#pragma unroll
    for (int q = 0; q < 4; ++q)
      o4[q] = make_float4(acc[q*4+0], acc[q*4+1], acc[q*4+2], acc[q*4+3]);
  }
}

// plain single-layer linrelu (msg1)
__global__ __launch_bounds__(256) void linrelu_kernel(
    const float* __restrict__ in, const float* __restrict__ W,
    const float* __restrict__ bias, float* __restrict__ out)
{
  const int tid = threadIdx.x;
  const int r = tid & 63, cg = tid >> 6;
  const size_t rowbase = (size_t)blockIdx.x * 64;
  __shared__ float xs[64 * 65];
  __shared__ float Ws[64 * 64];
  __shared__ float bs[64];
  float acc[16];
#pragma unroll
  for (int i = 0; i < 16; ++i) {
    int idx = tid + 256 * i;
    xs[(idx & 63) * 65 + (idx >> 6)] = in[rowbase * 64 + idx];
    Ws[idx] = W[idx];
  }
  if (tid < 64) bs[tid] = bias[tid];
  __syncthreads();
  mlp_layer(acc, xs, Ws, bs, r, cg);
  float4* o4 = (float4*)(out + (rowbase + r) * 64 + cg * 16);
#pragma unroll
  for (int q = 0; q < 4; ++q)
    o4[q] = make_float4(acc[q*4+0], acc[q*4+1], acc[q*4+2], acc[q*4+3]);
}

// Fused mp: S = h_tile . h^T (8 rows x 2048) with the S tile living in LDS,
// 512 threads (32 acc/thread, no spills at launch_bounds(512,2) = 256-reg cap),
// then WAVE-PRIVATE top-50 (wave r owns row r): adaptive radix select + extract
// + aggregation + update MLP with no block barriers (3 barriers total).
template <bool FINAL>
__global__ __launch_bounds__(512, 2) void mp_kernel(
    const float* __restrict__ h, const float* __restrict__ hT,
    const float* __restrict__ msg,
    const float* __restrict__ wu, const float* __restrict__ bu,
    float* __restrict__ outp, float* __restrict__ outT)
{
  const int tid = threadIdx.x;
  const int lane = tid & 63;
  const int w64 = tid >> 6;               // 8 waves <-> 8 rows
  const int bid = blockIdx.x;
  const int b = bid & 7;                  // round-robin blockIdx->XCD: 1 batch/XCD
  const int n0 = (bid >> 3) * 8;

  __shared__ unsigned Sbuf[8 * N_NODES];  // 64 KB: ordered-uint S tile
  __shared__ unsigned hist[8][HROW];      // per-wave radix histograms
  __shared__ float hrL[8 * 64];
  __shared__ unsigned gtc[8], eqc[8];
  __shared__ int seli[8][64];
  __shared__ float selv[8][64];
  __shared__ int eqlist[8][64];
  __shared__ float aggb[8 * 64];
  __shared__ float ot[64 * 9];

  const float* hb  = h  + (size_t)b * N_NODES * 64;
  const float* hTb = hT + (size_t)b * 64 * N_NODES;
  const float* colp = hTb + 4 * tid;      // 512 threads x 4 cols = 2048

  // prefetch ring depth 4 (issued before any LDS dependency)
  float4 pf[4];
#pragma unroll
  for (int i = 0; i < 4; ++i) pf[i] = *(const float4*)(colp + (size_t)i * 2048);

  hrL[tid] = hb[(size_t)n0 * 64 + tid];
  if (tid < 8) { gtc[tid] = 0; eqc[tid] = 0; }
  for (int i = tid; i < 8 * HROW; i += 512) (&hist[0][0])[i] = 0;
  __syncthreads();                                   // barrier 0: hrL/hist ready

  // ---- FMA phase: acc2[r*2+(e>>1)][e&1] = S[r][4*tid+e]
  v2f acc2[16];
#pragma unroll
  for (int i = 0; i < 16; ++i) { acc2[i][0] = 0.f; acc2[i][1] = 0.f; }

  for (int k4 = 0; k4 < 16; ++k4) {
    float4 a[8];
#pragma unroll
    for (int r = 0; r < 8; ++r)
      a[r] = *(const float4*)&hrL[r * 64 + k4 * 4];  // LDS broadcast (uniform)
#pragma unroll
    for (int kk = 0; kk < 4; ++kk) {
      const int k = k4 * 4 + kk;
      float4 cu = pf[k & 3];
      if (k + 4 < 64) pf[k & 3] = *(const float4*)(colp + (size_t)(k + 4) * 2048);
      v2f c00 = {cu.x, cu.y}, c01 = {cu.z, cu.w};
#pragma unroll
      for (int r = 0; r < 8; ++r) {
        const float ar = ((const float*)&a[r])[kk];
        v2f as = {ar, ar};
        acc2[r*2+0] = __builtin_elementwise_fma(as, c00, acc2[r*2+0]);
        acc2[r*2+1] = __builtin_elementwise_fma(as, c01, acc2[r*2+1]);
      }
    }
  }

  // ---- convert + park the S tile in LDS
#pragma unroll
  for (int r = 0; r < 8; ++r) {
    uint4 w;
    w.x = ford(acc2[r*2+0][0]); w.y = ford(acc2[r*2+0][1]);
    w.z = ford(acc2[r*2+1][0]); w.w = ford(acc2[r*2+1][1]);
    *(uint4*)&Sbuf[r * N_NODES + 4 * tid] = w;
  }
  __syncthreads();                                   // barrier 1: Sbuf ready

  // ======== wave-private selection: wave w64 owns row rw ========
  const int rw = w64;
  const unsigned* Srow = &Sbuf[rw * N_NODES];
  unsigned Lv, Tv;
  {
    // prefilter: L = wave-min of per-lane max (>=64 values >= L => L <= T); M = row max
    unsigned lmx = 0;
#pragma unroll
    for (int i = 0; i < 8; ++i) {
      uint4 q = *(const uint4*)&Srow[i * 256 + 4 * lane];
      unsigned m1 = q.x > q.y ? q.x : q.y, m2 = q.z > q.w ? q.z : q.w;
      unsigned m = m1 > m2 ? m1 : m2;
      lmx = lmx > m ? lmx : m;
    }
    unsigned mn = lmx, mx = lmx;
#pragma unroll
    for (int off = 32; off >= 1; off >>= 1) {
      unsigned o1 = (unsigned)__shfl_xor((int)mn, off, 64);
      unsigned o2 = (unsigned)__shfl_xor((int)mx, off, 64);
      mn = mn < o1 ? mn : o1;
      mx = mx > o2 ? mx : o2;
    }
    Lv = mn;
    unsigned Mv = mx;
    if (Lv == Mv) {
      Tv = Mv;                                       // >=64 copies of max
    } else {
      int skipb = __builtin_clz(Lv ^ Mv) >> 3;       // shared prefix bytes
      int sh = 24 - 8 * skipb;
      unsigned pv = (unsigned)(((unsigned long long)Lv) >> (sh + 8));
      unsigned Kc = KSEL;
      int mode = 0;                                  // 0=HIST 1=PROBE 2=DONE
      const int sub = lane & 1;
      unsigned* hrw = hist[rw];
      for (int it = 0; it < 5 && mode != 2; ++it) {
        if (mode == 0) {
          // populate (gated by prefilter + prefix)
#pragma unroll
          for (int i = 0; i < 8; ++i) {
            uint4 q = *(const uint4*)&Srow[i * 256 + 4 * lane];
            unsigned vv[4] = {q.x, q.y, q.z, q.w};
#pragma unroll
            for (int e = 0; e < 4; ++e) {
              unsigned v = vv[e];
              if (v >= Lv &&
                  (unsigned)(((unsigned long long)v) >> (sh + 8)) == pv)
                atomicAdd(&hrw[hidx((v >> sh) & 255u, sub)], 1u);
            }
          }
          // scan + re-zero (same wave: DS ops in order)
          uint4 q0 = *(const uint4*)&hrw[lane * 8];
          uint4 q1 = *(const uint4*)&hrw[lane * 8 + 4];
          *(uint4*)&hrw[lane * 8]     = make_uint4(0,0,0,0);
          *(uint4*)&hrw[lane * 8 + 4] = make_uint4(0,0,0,0);
          unsigned c0 = q0.x + q0.y, c1 = q0.z + q0.w;
          unsigned c2 = q1.x + q1.y, c3 = q1.z + q1.w;
          unsigned s0 = c0, s1 = c1, s2 = c2, s3 = c3;
#pragma unroll
          for (int off = 1; off < 64; off <<= 1) {
            unsigned t0=__shfl_down((int)s0,off,64), t1=__shfl_down((int)s1,off,64);
            unsigned t2=__shfl_down((int)s2,off,64), t3=__shfl_down((int)s3,off,64);
            if (lane + off < 64) { s0+=t0; s1+=t1; s2+=t2; s3+=t3; }
          }
          unsigned T1=(unsigned)__shfl((int)s1,0,64);
          unsigned T2=(unsigned)__shfl((int)s2,0,64);
          unsigned T3=(unsigned)__shfl((int)s3,0,64);
          unsigned cA[4] = {c0, c1, c2, c3};
          unsigned AA[4] = {s0 - c0 + T1 + T2 + T3, s1 - c1 + T2 + T3,
                            s2 - c2 + T3,           s3 - c3};
          int fg = -1;
#pragma unroll
          for (int g = 0; g < 4; ++g)
            if (AA[g] < Kc && Kc <= AA[g] + cA[g]) fg = g;
          unsigned long long mk = __ballot(fg >= 0);
          int src = __ffsll(mk) - 1;                 // exactly one lane fires
          unsigned bin = 0, nKc = 0, cnt = 0;
          if (fg >= 0) {
            bin = (unsigned)(fg * 64 + lane);
            nKc = Kc - AA[fg];
            cnt = cA[fg];
          }
          bin = (unsigned)__shfl((int)bin, src, 64);
          nKc = (unsigned)__shfl((int)nKc, src, 64);
          cnt = (unsigned)__shfl((int)cnt, src, 64);
          pv = (pv << 8) | bin;
          Kc = nKc;
          sh -= 8;
          if (sh < 0)        { Tv = pv; mode = 2; }
          else if (cnt == 1) mode = 1;
        } else {
          // PROBE: unique candidate with current prefix = T
          unsigned found = 0; bool has = false;
#pragma unroll
          for (int i = 0; i < 8; ++i) {
            uint4 q = *(const uint4*)&Srow[i * 256 + 4 * lane];
            unsigned vv[4] = {q.x, q.y, q.z, q.w};
#pragma unroll
            for (int e = 0; e < 4; ++e) {
              unsigned v = vv[e];
              if (v >= Lv &&
                  (unsigned)(((unsigned long long)v) >> (sh + 8)) == pv) {
                found = v; has = true;
              }
            }
          }
          unsigned long long mk = __ballot(has);
          int src = __ffsll(mk) - 1;
          Tv = (unsigned)__shfl((int)found, src, 64);
          mode = 2;
        }
      }
    }
  }

  // ---- extract winners (> T) and tie candidates (== T), ballot-compacted
#pragma unroll
  for (int i = 0; i < 8; ++i) {
    uint4 q = *(const uint4*)&Srow[i * 256 + 4 * lane];
    unsigned vv[4] = {q.x, q.y, q.z, q.w};
#pragma unroll
    for (int e = 0; e < 4; ++e) {
      const unsigned v = vv[e];
      const int m = i * 256 + 4 * lane + e;
      unsigned long long mk = __ballot(v > Tv);
      if (mk) {
        int fs = __ffsll(mk) - 1;
        unsigned base = 0;
        if (lane == fs) base = atomicAdd(&gtc[rw], (unsigned)__popcll(mk));
        base = (unsigned)__shfl((int)base, fs, 64);
        if (v > Tv) {
          int pos = (int)base + __popcll(mk & ((1ULL << lane) - 1ULL));
          seli[rw][pos] = m; selv[rw][pos] = funord(v);
        }
      }
      unsigned long long mk2 = __ballot(v == Tv);
      if (mk2) {
        int fs = __ffsll(mk2) - 1;
        unsigned base = 0;
        if (lane == fs) base = atomicAdd(&eqc[rw], (unsigned)__popcll(mk2));
        base = (unsigned)__shfl((int)base, fs, 64);
        if (v == Tv) {
          int pos = (int)base + __popcll(mk2 & ((1ULL << lane) - 1ULL));
          if (pos < 64) eqlist[rw][pos] = m;
        }
      }
    }
  }

  // ---- resolve ties (lane 0 of each wave; jax order: smallest indices)
  const int gW = (int)gtc[rw];
  const int needW = KSEL - gW;
  if (lane == 0) {
    const int e = (eqc[rw] < 64u) ? (int)eqc[rw] : 64;
    const float Tf = funord(Tv);
    for (int t = 0; t < needW; ++t) {
      int bestp = -1, bestm = 0x7FFFFFFF;
      for (int i = 0; i < e; ++i) {
        int mm = eqlist[rw][i];
        if (mm < bestm) { bestm = mm; bestp = i; }
      }
      if (bestp < 0) break;
      eqlist[rw][bestp] = 0x7FFFFFFF;
      seli[rw][gW + t] = bestm;
      selv[rw][gW + t] = Tf;
    }
  }

  if constexpr (FINAL) {
    float* ob = outp + ((size_t)b * N_NODES + n0 + rw) * N_NODES;
#pragma unroll
    for (int i = 0; i < 8; ++i) {
      uint4 q = *(const uint4*)&Srow[i * 256 + 4 * lane];
      unsigned vv[4] = {q.x, q.y, q.z, q.w};
      float4 w; float* wf = (float*)&w;
#pragma unroll
      for (int e = 0; e < 4; ++e) {
        const unsigned v = vv[e];
        const int m = i * 256 + 4 * lane + e;
        bool keep = v > Tv;
        if (v == Tv) {
          for (int t = 0; t < needW; ++t)
            if (seli[rw][gW + t] == m) { keep = true; break; }
        }
        wf[e] = keep ? funord(v) : 0.f;
      }
      *(float4*)(ob + i * 256 + 4 * lane) = w;
    }
  } else {
    // aggregation: wave rw, feature f = lane
    {
      const float* msgb = msg + (size_t)b * N_NODES * 64;
      float a = 0.f;
      for (int i = 0; i < KSEL; ++i) {
        int mi = seli[rw][i];                  // wave-uniform LDS broadcast
        float vvv = selv[rw][i];
        a += vvv * msgb[(size_t)mi * 64 + lane];
      }
      aggb[rw * 64 + lane] = a;
    }
    // update MLP: out h2[rw][c=lane]
    float s = bu[lane];
#pragma unroll 8
    for (int jj = 0; jj < 64; ++jj)
      s += hrL[rw * 64 + jj] * wu[jj * 64 + lane];
#pragma unroll 8
    for (int jj = 0; jj < 64; ++jj)
      s += aggb[rw * 64 + jj] * wu[(64 + jj) * 64 + lane];
    s = fmaxf(s, 0.f);
    outp[((size_t)b * N_NODES + n0 + rw) * 64 + lane] = s;
    ot[lane * 9 + rw] = s;                     // stride 9: conflict-free
    __syncthreads();                           // barrier 2: ot staging
    {
      int f = tid >> 3, rr = tid & 7;
      outT[(size_t)b * 64 * N_NODES + (size_t)f * N_NODES + n0 + rr] = ot[f * 9 + rr];
    }
  }
}

extern "C" void kernel_launch(void* const* d_in, const int* in_sizes, int n_in,
                              void* d_out, int out_size, void* d_ws, size_t ws_size,
                              hipStream_t stream)
{
  (void)in_sizes; (void)n_in; (void)out_size; (void)ws_size;
  const float* x   = (const float*)d_in[0];
  const float* ew0 = (const float*)d_in[1];
  const float* eb0 = (const float*)d_in[2];
  const float* ew1 = (const float*)d_in[3];
  const float* eb1 = (const float*)d_in[4];
  const float* w0m = (const float*)d_in[5];
  const float* b0m = (const float*)d_in[6];
  const float* w0u = (const float*)d_in[7];
  const float* b0u = (const float*)d_in[8];
  const float* w1m = (const float*)d_in[9];
  const float* b1m = (const float*)d_in[10];
  const float* w1u = (const float*)d_in[11];
  const float* b1u = (const float*)d_in[12];
  float* out = (float*)d_out;
  float* ws = (float*)d_ws;

  const size_t BUF = (size_t)8 * N_NODES * 64;  // 4 MB each, 20 MB total
  float* A   = ws;
  float* AT  = ws + 1 * BUF;
  float* Bf  = ws + 2 * BUF;
  float* BfT = ws + 3 * BUF;
  float* C   = ws + 4 * BUF;

  // fused embedding (2 layers) + msg0
  emb3_kernel<<<256, 256, 0, stream>>>(x, ew0, eb0, ew1, eb1, w0m, b0m, A, AT, C);

  // MP layer 0 (consumes msg0=C, produces Bf/BfT)
  mp_kernel<false><<<2048, 512, 0, stream>>>(A, AT, C, w0u, b0u, Bf, BfT);

  // msg1
  linrelu_kernel<<<256, 256, 0, stream>>>(Bf, w1m, b1m, C);

  // MP layer 1
  mp_kernel<false><<<2048, 512, 0, stream>>>(Bf, BfT, C, w1u, b1u, A, AT);

  // final dense top-k adjacency
  mp_kernel<true><<<2048, 512, 0, stream>>>(A, AT, nullptr, nullptr, nullptr, out, nullptr);
}

// Round 8
// 626.857 us; speedup vs baseline: 8.1071x; 1.1948x over previous
//
#include <hip/hip_runtime.h>

#define N_NODES 2048
#define KSEL 50

typedef float v2f __attribute__((ext_vector_type(2)));

// ---- order-preserving fp32 <-> uint map (monotone: bigger float => bigger uint)
__device__ __forceinline__ unsigned ford(float f) {
  unsigned b = __float_as_uint(f);
  return b ^ ((b & 0x80000000u) ? 0xFFFFFFFFu : 0x80000000u);
}
__device__ __forceinline__ float funord(unsigned u) {
  unsigned b = (u & 0x80000000u) ? (u ^ 0x80000000u) : ~u;
  return __uint_as_float(b);
}

// 1-sub-counter hist layout: bin b -> word ((b&63)<<2)|(b>>6).
// Scan: lane reads uint4 at [lane*4] = bins {g*64+lane}, g=0..3 (components).
__device__ __forceinline__ int hidx1(unsigned b) {
  return (int)(((b & 63u) << 2) | (b >> 6));
}

// shared single-layer MLP tile: acc[16] = relu(bias + xs^T W), xs transposed layout
__device__ __forceinline__ void mlp_layer(float acc[16], const float* xs,
                                          const float* Ws, const float* bs,
                                          int r, int cg) {
  const float4* Ws4 = (const float4*)Ws;
#pragma unroll
  for (int i = 0; i < 16; ++i) acc[i] = bs[cg * 16 + i];
#pragma unroll 8
  for (int k = 0; k < 64; ++k) {
    float xv = xs[k * 65 + r];
    float4 w0 = Ws4[k * 16 + cg * 4 + 0];
    float4 w1 = Ws4[k * 16 + cg * 4 + 1];
    float4 w2 = Ws4[k * 16 + cg * 4 + 2];
    float4 w3 = Ws4[k * 16 + cg * 4 + 3];
    acc[0]  += xv * w0.x; acc[1]  += xv * w0.y; acc[2]  += xv * w0.z; acc[3]  += xv * w0.w;
    acc[4]  += xv * w1.x; acc[5]  += xv * w1.y; acc[6]  += xv * w1.z; acc[7]  += xv * w1.w;
    acc[8]  += xv * w2.x; acc[9]  += xv * w2.y; acc[10] += xv * w2.z; acc[11] += xv * w2.w;
    acc[12] += xv * w3.x; acc[13] += xv * w3.y; acc[14] += xv * w3.z; acc[15] += xv * w3.w;
  }
#pragma unroll
  for (int i = 0; i < 16; ++i) acc[i] = fmaxf(acc[i], 0.f);
}

// Fused embedding: h1=relu(x@w0+b0); h2=relu(h1@w1+b1) -> A, AT; msg0=relu(h2@wm+bm) -> M
__global__ __launch_bounds__(256) void emb3_kernel(
    const float* __restrict__ x,
    const float* __restrict__ ew0, const float* __restrict__ eb0,
    const float* __restrict__ ew1, const float* __restrict__ eb1,
    const float* __restrict__ wmm, const float* __restrict__ bmm,
    float* __restrict__ outA, float* __restrict__ outAT, float* __restrict__ outM)
{
  const int tid = threadIdx.x;
  const int r = tid & 63, cg = tid >> 6;
  const size_t rowbase = (size_t)blockIdx.x * 64;
  __shared__ float xs[64 * 65];
  __shared__ float Ws[64 * 64];
  __shared__ float bs[64];
  float acc[16];

#pragma unroll
  for (int i = 0; i < 16; ++i) {
    int idx = tid + 256 * i;
    xs[(idx & 63) * 65 + (idx >> 6)] = x[rowbase * 64 + idx];
    Ws[idx] = ew0[idx];
  }
  if (tid < 64) bs[tid] = eb0[tid];
  __syncthreads();
  mlp_layer(acc, xs, Ws, bs, r, cg);             // h1
  __syncthreads();
#pragma unroll
  for (int i = 0; i < 16; ++i) {
    xs[(cg * 16 + i) * 65 + r] = acc[i];
    Ws[tid + 256 * i] = ew1[tid + 256 * i];
  }
  if (tid < 64) bs[tid] = eb1[tid];
  __syncthreads();
  mlp_layer(acc, xs, Ws, bs, r, cg);             // h2
  {
    float4* o4 = (float4*)(outA + (rowbase + r) * 64 + cg * 16);
#pragma unroll
    for (int q = 0; q < 4; ++q)
      o4[q] = make_float4(acc[q*4+0], acc[q*4+1], acc[q*4+2], acc[q*4+3]);
  }
  __syncthreads();
#pragma unroll
  for (int i = 0; i < 16; ++i) {
    xs[(cg * 16 + i) * 65 + r] = acc[i];
    Ws[tid + 256 * i] = wmm[tid + 256 * i];
  }
  if (tid < 64) bs[tid] = bmm[tid];
  __syncthreads();
  {   // flush AT (h2 transposed, feature-major)
    const size_t bb = rowbase >> 11;
    const int nbase = (int)(rowbase & 2047);
    const int c = tid >> 2, seg = tid & 3;
    float* oT = outAT + bb * 64 * N_NODES + (size_t)c * N_NODES + nbase + seg * 16;
#pragma unroll
    for (int q = 0; q < 4; ++q)
      ((float4*)oT)[q] = make_float4(xs[c*65+seg*16+q*4+0], xs[c*65+seg*16+q*4+1],
                                     xs[c*65+seg*16+q*4+2], xs[c*65+seg*16+q*4+3]);
  }
  mlp_layer(acc, xs, Ws, bs, r, cg);             // msg0
  {
    float4* o4 = (float4*)(outM + (rowbase + r) * 64 + cg * 16);
#pragma unroll
    for (int q = 0; q < 4; ++q)
      o4[q] = make_float4(acc[q*4+0], acc[q*4+1], acc[q*4+2], acc[q*4+3]);
  }
}

// plain single-layer linrelu (msg1)
__global__ __launch_bounds__(256) void linrelu_kernel(
    const float* __restrict__ in, const float* __restrict__ W,
    const float* __restrict__ bias, float* __restrict__ out)
{
  const int tid = threadIdx.x;
  const int r = tid & 63, cg = tid >> 6;
  const size_t rowbase = (size_t)blockIdx.x * 64;
  __shared__ float xs[64 * 65];
  __shared__ float Ws[64 * 64];
  __shared__ float bs[64];
  float acc[16];
#pragma unroll
  for (int i = 0; i < 16; ++i) {
    int idx = tid + 256 * i;
    xs[(idx & 63) * 65 + (idx >> 6)] = in[rowbase * 64 + idx];
    Ws[idx] = W[idx];
  }
  if (tid < 64) bs[tid] = bias[tid];
  __syncthreads();
  mlp_layer(acc, xs, Ws, bs, r, cg);
  float4* o4 = (float4*)(out + (rowbase + r) * 64 + cg * 16);
#pragma unroll
  for (int q = 0; q < 4; ++q)
    o4[q] = make_float4(acc[q*4+0], acc[q*4+1], acc[q*4+2], acc[q*4+3]);
}

// Fused mp: S = h_tile . h^T in LDS (Sbuf), 512 thr, <=80 KB LDS -> 2 blocks/CU
// so select of block A overlaps FMA of block B. Wave-private top-50 (wave r owns
// row r): reg-based prefilter, adaptive 1-sub radix, scan-compacted extraction.
template <bool FINAL>
__global__ __launch_bounds__(512, 4) void mp_kernel(
    const float* __restrict__ h, const float* __restrict__ hT,
    const float* __restrict__ msg,
    const float* __restrict__ wu, const float* __restrict__ bu,
    float* __restrict__ outp, float* __restrict__ outT)
{
  const int tid = threadIdx.x;
  const int lane = tid & 63;
  const int w64 = tid >> 6;               // 8 waves <-> 8 rows
  const int bid = blockIdx.x;
  const int b = bid & 7;                  // round-robin blockIdx->XCD: 1 batch/XCD
  const int n0 = (bid >> 3) * 8;

  __shared__ unsigned Sbuf[8 * N_NODES];  // 64 KB ordered-uint S tile (+overlays)
  __shared__ unsigned hist[8][256];       // per-wave radix histograms (8 KB)
  __shared__ float hrL[8 * 64];           // MP epilogue row tile
  __shared__ unsigned LwMin[8][8], LwMax[8][8];   // [wave][row] prefilter staging
  __shared__ int   seli[8][52];
  __shared__ float selv[8][52];
  __shared__ int   eqlist[8][64];

  const float* hb  = h  + (size_t)b * N_NODES * 64;
  const float* hTb = hT + (size_t)b * 64 * N_NODES;
  const float* colp = hTb + 4 * tid;      // 512 threads x 4 cols = 2048

  // prefetch ring depth 4 (issued before anything else)
  float4 pf[4];
#pragma unroll
  for (int i = 0; i < 4; ++i) pf[i] = *(const float4*)(colp + (size_t)i * 2048);

  if (!FINAL) hrL[tid] = hb[(size_t)n0 * 64 + tid];
  for (int i = tid; i < 8 * 256; i += 512) (&hist[0][0])[i] = 0;

  // ---- FMA phase: acc2[r*2+(e>>1)][e&1] = S[r][4*tid+e]; rows via s_load
  v2f acc2[16];
#pragma unroll
  for (int i = 0; i < 16; ++i) { acc2[i][0] = 0.f; acc2[i][1] = 0.f; }

  const float* hrow = hb + (size_t)n0 * 64;        // block-uniform -> SGPR loads
  for (int k4 = 0; k4 < 16; ++k4) {
    float4 a[8];
#pragma unroll
    for (int r = 0; r < 8; ++r)
      a[r] = *(const float4*)(hrow + r * 64 + k4 * 4);
#pragma unroll
    for (int kk = 0; kk < 4; ++kk) {
      const int k = k4 * 4 + kk;
      float4 cu = pf[kk];
      if (k + 4 < 64) pf[kk] = *(const float4*)(colp + (size_t)(k + 4) * 2048);
      v2f c00 = {cu.x, cu.y}, c01 = {cu.z, cu.w};
#pragma unroll
      for (int r = 0; r < 8; ++r) {
        const float ar = ((const float*)&a[r])[kk];
        v2f as = {ar, ar};
        acc2[r*2+0] = __builtin_elementwise_fma(as, c00, acc2[r*2+0]);
        acc2[r*2+1] = __builtin_elementwise_fma(as, c01, acc2[r*2+1]);
      }
    }
  }

  // ---- convert, park in LDS, and compute reg-based prefilter reductions
#pragma unroll
  for (int r = 0; r < 8; ++r) {
    uint4 w;
    w.x = ford(acc2[r*2+0][0]); w.y = ford(acc2[r*2+0][1]);
    w.z = ford(acc2[r*2+1][0]); w.w = ford(acc2[r*2+1][1]);
    *(uint4*)&Sbuf[r * N_NODES + 4 * tid] = w;
    unsigned m1 = w.x > w.y ? w.x : w.y, m2 = w.z > w.w ? w.z : w.w;
    unsigned lm = m1 > m2 ? m1 : m2;           // per-lane max of its 4 vals
    unsigned mn = lm, mx = lm;
#pragma unroll
    for (int off = 32; off >= 1; off >>= 1) {
      unsigned o1 = (unsigned)__shfl_xor((int)mn, off, 64);
      unsigned o2 = (unsigned)__shfl_xor((int)mx, off, 64);
      mn = mn < o1 ? mn : o1;                  // wave-min of lane maxes
      mx = mx > o2 ? mx : o2;                  // wave-max
    }
    if (lane == 0) { LwMin[w64][r] = mn; LwMax[w64][r] = mx; }
  }
  __syncthreads();                             // barrier 1: Sbuf/LwMM/hist/hrL

  // ======== wave-private selection: wave w64 owns row rw ========
  const int rw = w64;
  const unsigned* Srow = &Sbuf[rw * N_NODES];
  unsigned Lv, Tv;
  {
    unsigned lmn = (lane < 8) ? LwMin[lane][rw] : 0u;
    unsigned lmx = (lane < 8) ? LwMax[lane][rw] : 0u;
#pragma unroll
    for (int off = 4; off >= 1; off >>= 1) {
      unsigned o1 = (unsigned)__shfl_xor((int)lmn, off, 8);
      unsigned o2 = (unsigned)__shfl_xor((int)lmx, off, 8);
      lmn = lmn > o1 ? lmn : o1;               // L = max over waves of wave-mins
      lmx = lmx > o2 ? lmx : o2;               // M = row max
    }
    Lv = (unsigned)__shfl((int)lmn, 0, 64);
    unsigned Mv = (unsigned)__shfl((int)lmx, 0, 64);

    if (Lv == Mv) {
      Tv = Mv;                                 // >=64 copies of the max
    } else {
      int sh = 24 - 8 * (__builtin_clz(Lv ^ Mv) >> 3);
      unsigned pv = (unsigned)(((unsigned long long)Lv) >> (sh + 8));
      unsigned Kc = KSEL;
      int mode = 0;                            // 0=HIST 1=PROBE 2=DONE
      unsigned* hrw = hist[rw];
      for (int it = 0; it < 5 && mode != 2; ++it) {
        if (mode == 0) {
#pragma unroll
          for (int i = 0; i < 8; ++i) {
            uint4 q = *(const uint4*)&Srow[i * 256 + 4 * lane];
            unsigned vv[4] = {q.x, q.y, q.z, q.w};
#pragma unroll
            for (int e = 0; e < 4; ++e) {
              unsigned v = vv[e];
              if (v >= Lv &&
                  (unsigned)(((unsigned long long)v) >> (sh + 8)) == pv)
                atomicAdd(&hrw[hidx1((v >> sh) & 255u)], 1u);
            }
          }
          uint4 q = *(const uint4*)&hrw[lane * 4];
          *(uint4*)&hrw[lane * 4] = make_uint4(0, 0, 0, 0);
          unsigned c0 = q.x, c1 = q.y, c2 = q.z, c3 = q.w;
          unsigned s0 = c0, s1 = c1, s2 = c2, s3 = c3;   // suffix over lanes
#pragma unroll
          for (int off = 1; off < 64; off <<= 1) {
            unsigned t0=__shfl_down((int)s0,off,64), t1=__shfl_down((int)s1,off,64);
            unsigned t2=__shfl_down((int)s2,off,64), t3=__shfl_down((int)s3,off,64);
            if (lane + off < 64) { s0+=t0; s1+=t1; s2+=t2; s3+=t3; }
          }
          unsigned T1=(unsigned)__shfl((int)s1,0,64);
          unsigned T2=(unsigned)__shfl((int)s2,0,64);
          unsigned T3=(unsigned)__shfl((int)s3,0,64);
          unsigned cA[4] = {c0, c1, c2, c3};
          unsigned AA[4] = {s0 - c0 + T1 + T2 + T3, s1 - c1 + T2 + T3,
                            s2 - c2 + T3,           s3 - c3};
          int fg = -1;
#pragma unroll
          for (int g = 0; g < 4; ++g)
            if (AA[g] < Kc && Kc <= AA[g] + cA[g]) fg = g;
          unsigned long long mk = __ballot(fg >= 0);
          int src = __ffsll(mk) - 1;           // exactly one lane fires
          unsigned bin = 0, nKc = 0, cnt = 0;
          if (fg >= 0) {
            bin = (unsigned)(fg * 64 + lane);
            nKc = Kc - AA[fg];
            cnt = cA[fg];
          }
          bin = (unsigned)__shfl((int)bin, src, 64);
          nKc = (unsigned)__shfl((int)nKc, src, 64);
          cnt = (unsigned)__shfl((int)cnt, src, 64);
          pv = (pv << 8) | bin;
          Kc = nKc;
          sh -= 8;
          if (sh < 0)        { Tv = pv; mode = 2; }
          else if (cnt == 1) mode = 1;
        } else {
          // PROBE: the unique candidate with this prefix is T
          unsigned found = 0; bool has = false;
#pragma unroll
          for (int i = 0; i < 8; ++i) {
            uint4 q = *(const uint4*)&Srow[i * 256 + 4 * lane];
            unsigned vv[4] = {q.x, q.y, q.z, q.w};
#pragma unroll
            for (int e = 0; e < 4; ++e) {
              unsigned v = vv[e];
              if (v >= Lv &&
                  (unsigned)(((unsigned long long)v) >> (sh + 8)) == pv) {
                found = v; has = true;
              }
            }
          }
          unsigned long long mk = __ballot(has);
          int src = __ffsll(mk) - 1;
          Tv = (unsigned)__shfl((int)found, src, 64);
          mode = 2;
        }
      }
    }
  }

  // ---- extraction: per-lane counts + wave prefix scans (no ballots/atomics)
  unsigned vals[32];
  int cgt = 0, ceq = 0;
#pragma unroll
  for (int i = 0; i < 8; ++i) {
    uint4 q = *(const uint4*)&Srow[i * 256 + 4 * lane];
    vals[i*4+0] = q.x; vals[i*4+1] = q.y; vals[i*4+2] = q.z; vals[i*4+3] = q.w;
#pragma unroll
    for (int e = 0; e < 4; ++e) {
      cgt += (vals[i*4+e] > Tv);
      ceq += (vals[i*4+e] == Tv);
    }
  }
  int sg = cgt, se = ceq;
#pragma unroll
  for (int off = 1; off < 64; off <<= 1) {
    int t0 = __shfl_up(sg, off, 64), t1 = __shfl_up(se, off, 64);
    if (lane >= off) { sg += t0; se += t1; }
  }
  const int gW = __shfl(sg, 63, 64);           // total winners (> T), < 50
  const int eTot = __shfl(se, 63, 64);
  int gb = sg - cgt, eb = se - ceq;            // exclusive bases
#pragma unroll
  for (int i = 0; i < 8; ++i) {
#pragma unroll
    for (int e = 0; e < 4; ++e) {
      unsigned v = vals[i*4+e];
      int m = i * 256 + 4 * lane + e;
      if (v > Tv) { seli[rw][gb] = m; selv[rw][gb] = funord(v); ++gb; }
      else if (v == Tv) { if (eb < 64) eqlist[rw][eb] = m; ++eb; }
    }
  }
  const int eW = eTot < 64 ? eTot : 64;

  // ---- tie-resolve, wave-parallel: `need` smallest indices among equals
  const int needW = KSEL - gW;
  {
    const float Tf = funord(Tv);
    int myi = (lane < eW) ? eqlist[rw][lane] : 0x7FFFFFFF;
    for (int t = 0; t < needW; ++t) {
      int mn = myi;
#pragma unroll
      for (int off = 32; off >= 1; off >>= 1) {
        int o = __shfl_xor(mn, off, 64);
        mn = mn < o ? mn : o;
      }
      if (mn == 0x7FFFFFFF) break;
      if (myi == mn) {
        seli[rw][gW + t] = mn; selv[rw][gW + t] = Tf;
        myi = 0x7FFFFFFF;
      }
    }
  }

  if constexpr (FINAL) {
    float* ob = outp + ((size_t)b * N_NODES + n0 + rw) * N_NODES;
#pragma unroll
    for (int i = 0; i < 8; ++i) {
      float4 w; float* wf = (float*)&w;
#pragma unroll
      for (int e = 0; e < 4; ++e) {
        const unsigned v = vals[i*4+e];
        const int m = i * 256 + 4 * lane + e;
        bool keep = v > Tv;
        if (v == Tv) {
          for (int t = 0; t < needW; ++t)
            if (seli[rw][gW + t] == m) { keep = true; break; }
        }
        wf[e] = keep ? funord(v) : 0.f;
      }
      *(float4*)(ob + i * 256 + 4 * lane) = w;
    }
  } else {
    // aggregation into per-row Sbuf overlay (wave-private region)
    float* aggbR = (float*)&Sbuf[rw * N_NODES + 1024];
    {
      const float* msgb = msg + (size_t)b * N_NODES * 64;
      float a = 0.f;
      for (int i = 0; i < KSEL; ++i) {
        int mi = seli[rw][i];                  // wave-uniform LDS broadcast
        float vvv = selv[rw][i];
        a += vvv * msgb[(size_t)mi * 64 + lane];
      }
      aggbR[lane] = a;
    }
    // update MLP: h2[rw][lane]
    float s = bu[lane];
#pragma unroll 8
    for (int jj = 0; jj < 64; ++jj)
      s += hrL[rw * 64 + jj] * wu[jj * 64 + lane];
#pragma unroll 8
    for (int jj = 0; jj < 64; ++jj)
      s += aggbR[jj] * wu[(64 + jj) * 64 + lane];
    s = fmaxf(s, 0.f);
    outp[((size_t)b * N_NODES + n0 + rw) * 64 + lane] = s;
    __syncthreads();                           // all waves done with Sbuf
    float* otF = (float*)Sbuf;                 // transpose staging overlay
    otF[lane * 9 + rw] = s;                    // stride 9: conflict-free
    __syncthreads();
    {
      int f = tid >> 3, rr = tid & 7;
      outT[(size_t)b * 64 * N_NODES + (size_t)f * N_NODES + n0 + rr] = otF[f * 9 + rr];
    }
  }
}

extern "C" void kernel_launch(void* const* d_in, const int* in_sizes, int n_in,
                              void* d_out, int out_size, void* d_ws, size_t ws_size,
                              hipStream_t stream)
{
  (void)in_sizes; (void)n_in; (void)out_size; (void)ws_size;
  const float* x   = (const float*)d_in[0];
  const float* ew0 = (const float*)d_in[1];
  const float* eb0 = (const float*)d_in[2];
  const float* ew1 = (const float*)d_in[3];
  const float* eb1 = (const float*)d_in[4];
  const float* w0m = (const float*)d_in[5];
  const float* b0m = (const float*)d_in[6];
  const float* w0u = (const float*)d_in[7];
  const float* b0u = (const float*)d_in[8];
  const float* w1m = (const float*)d_in[9];
  const float* b1m = (const float*)d_in[10];
  const float* w1u = (const float*)d_in[11];
  const float* b1u = (const float*)d_in[12];
  float* out = (float*)d_out;
  float* ws = (float*)d_ws;

  const size_t BUF = (size_t)8 * N_NODES * 64;  // 4 MB each, 20 MB total
  float* A   = ws;
  float* AT  = ws + 1 * BUF;
  float* Bf  = ws + 2 * BUF;
  float* BfT = ws + 3 * BUF;
  float* C   = ws + 4 * BUF;

  // fused embedding (2 layers) + msg0
  emb3_kernel<<<256, 256, 0, stream>>>(x, ew0, eb0, ew1, eb1, w0m, b0m, A, AT, C);

  // MP layer 0 (consumes msg0=C, produces Bf/BfT)
  mp_kernel<false><<<2048, 512, 0, stream>>>(A, AT, C, w0u, b0u, Bf, BfT);

  // msg1
  linrelu_kernel<<<256, 256, 0, stream>>>(Bf, w1m, b1m, C);

  // MP layer 1
  mp_kernel<false><<<2048, 512, 0, stream>>>(Bf, BfT, C, w1u, b1u, A, AT);

  // final dense top-k adjacency
  mp_kernel<true><<<2048, 512, 0, stream>>>(A, AT, nullptr, nullptr, nullptr, out, nullptr);
}